// Round 1
// baseline (211.079 us; speedup 1.0000x reference)
//
#include <hip/hip_runtime.h>

// ---------- types ----------
typedef __attribute__((ext_vector_type(8))) short bh8;           // 8 bf16 in 4 VGPRs (MFMA operand)
typedef __attribute__((ext_vector_type(4))) float f4;            // MFMA accumulator
typedef __attribute__((ext_vector_type(4))) unsigned short us4;

__device__ __forceinline__ unsigned short rne_bf16(float x) {
  unsigned int u = __builtin_bit_cast(unsigned int, x);
  u += 0x7fffu + ((u >> 16) & 1u);
  return (unsigned short)(u >> 16);
}

// Byte offset of element (row, k) in a swizzled [rows][64] bf16 LDS tile (128B rows).
// 16B-group index XOR-ed with row bits -> frag reads spread across banks.
__device__ __forceinline__ int swz(int row, int k) {
  return row * 128 + ((((k >> 3) ^ row ^ (row >> 3)) & 7) << 4) + ((k & 7) << 1);
}

__device__ __forceinline__ void gl_lds16(const void* g, void* l) {
  __builtin_amdgcn_global_load_lds(
      (const __attribute__((address_space(1))) void*)g,
      (__attribute__((address_space(3))) void*)l, 16, 0, 0);
}

// ---------- prepass: fp32 -> bf16 ----------
__global__ void cvt_bf16_kernel(const float* __restrict__ in, unsigned short* __restrict__ out, int n4) {
  int i = blockIdx.x * blockDim.x + threadIdx.x;
  int stride = gridDim.x * blockDim.x;
  for (; i < n4; i += stride) {
    f4 v = *(const f4*)(in + (long)i * 4);
    us4 o;
#pragma unroll
    for (int j = 0; j < 4; ++j) o[j] = rne_bf16(v[j]);
    *(us4*)(out + (long)i * 4) = o;
  }
}

// ---------- prepass: W[K][N] fp32 -> Wt[N][K] bf16 ----------
__global__ void transpose_cvt(const float* __restrict__ in, unsigned short* __restrict__ out,
                              int K, int N) {
  __shared__ float t[32][33];
  int n0 = blockIdx.x * 32, k0 = blockIdx.y * 32;
  int tx = threadIdx.x & 31, ty = threadIdx.x >> 5;  // ty 0..7
#pragma unroll
  for (int r = 0; r < 32; r += 8)
    t[ty + r][tx] = in[(long)(k0 + ty + r) * N + n0 + tx];
  __syncthreads();
#pragma unroll
  for (int r = 0; r < 32; r += 8)
    out[(long)(n0 + ty + r) * K + k0 + tx] = rne_bf16(t[tx][ty + r]);
}

// ---------- generic bf16 GEMM: C[m][n] = sum_k A[m][k] * Bt[n][k] ----------
// MODE 0: store bf16.  MODE 1: store f32 * scale.  MODE 2: store f32 + bias[n].
template <int MODE>
__global__ __launch_bounds__(256, 2) void gemm_bt(
    const unsigned short* __restrict__ A, const unsigned short* __restrict__ Bt,
    void* __restrict__ Cv, int K, int lda, int ldb, int ldc,
    long astr, long bstr, long cstr, float scale, const float* __restrict__ bias) {
  __shared__ unsigned short As[128 * 64];
  __shared__ unsigned short Bs[128 * 64];
  const int tid = threadIdx.x, w = tid >> 6, l = tid & 63;
  const int c = l & 15, g = l >> 4;
  const int m0 = blockIdx.y * 128, n0 = blockIdx.x * 128;
  const unsigned short* Ab = A + (long)blockIdx.z * astr;
  const unsigned short* Bb = Bt + (long)blockIdx.z * bstr;

  f4 acc[4][4];
#pragma unroll
  for (int i = 0; i < 4; ++i)
#pragma unroll
    for (int j = 0; j < 4; ++j) acc[i][j] = (f4){0.f, 0.f, 0.f, 0.f};

  const int nkt = K >> 6;
  for (int kt = 0; kt < nkt; ++kt) {
    if (kt) __syncthreads();
#pragma unroll
    for (int s = 0; s < 4; ++s) {
      const int idx = w * 4 + s;               // wave-uniform LDS dest
      const int row = idx * 8 + (l >> 3);
      const int k0 = (((l & 7) ^ row ^ (row >> 3)) & 7) << 3;  // inverse swizzle on source
      gl_lds16(Ab + (long)(m0 + row) * lda + kt * 64 + k0, (char*)As + idx * 1024);
      gl_lds16(Bb + (long)(n0 + row) * ldb + kt * 64 + k0, (char*)Bs + idx * 1024);
    }
    asm volatile("s_waitcnt vmcnt(0)" ::: "memory");
    __syncthreads();
#pragma unroll
    for (int kk = 0; kk < 2; ++kk) {
      const int k = kk * 32 + g * 8;
      bh8 af[4], bfr[4];
#pragma unroll
      for (int i = 0; i < 4; ++i) {
        af[i] = *(const bh8*)((const char*)As + swz((w >> 1) * 64 + i * 16 + c, k));
        bfr[i] = *(const bh8*)((const char*)Bs + swz((w & 1) * 64 + i * 16 + c, k));
      }
#pragma unroll
      for (int i = 0; i < 4; ++i)
#pragma unroll
        for (int j = 0; j < 4; ++j)
          acc[i][j] = __builtin_amdgcn_mfma_f32_16x16x32_bf16(af[i], bfr[j], acc[i][j], 0, 0, 0);
    }
  }

  const int rbase = m0 + (w >> 1) * 64, cbase = n0 + (w & 1) * 64;
#pragma unroll
  for (int i = 0; i < 4; ++i)
#pragma unroll
    for (int j = 0; j < 4; ++j)
#pragma unroll
      for (int r = 0; r < 4; ++r) {
        const long row = rbase + i * 16 + g * 4 + r;
        const long col = cbase + j * 16 + c;
        const float v = acc[i][j][r];
        if (MODE == 0) {
          ((unsigned short*)Cv + (long)blockIdx.z * cstr)[row * ldc + col] = rne_bf16(v);
        } else if (MODE == 1) {
          ((float*)Cv + (long)blockIdx.z * cstr)[row * ldc + col] = v * scale;
        } else {
          ((float*)Cv)[row * ldc + col] = v + bias[col];
        }
      }
}

// ---------- fused two-query flash attention ----------
// Qb: [8192][512] bf16 (projected).  adapt: [8192][512] fp32 (raw second query).
// KV: [2048][1024] bf16 (cols 0..511 = K-proj, 512..1023 = V-proj).
// Ob: [8192][512] bf16, merged-head attention output (sum of both passes, each normalized).
__global__ __launch_bounds__(256, 2) void attn_kernel(
    const unsigned short* __restrict__ Qb, const float* __restrict__ adapt,
    const unsigned short* __restrict__ KV, unsigned short* __restrict__ Ob) {
  __shared__ unsigned short Ks[64 * 64];      // swizzled [j][d]
  __shared__ unsigned short Vt[64 * 64];      // swizzled, transposed: (row=d, col=j)
  __shared__ unsigned short Ps[4][16 * 72];   // per-wave P tile, padded rows
  const int qt = blockIdx.x, h = blockIdx.y, b = blockIdx.z;
  const int tid = threadIdx.x, w = tid >> 6, l = tid & 63;
  const int c = l & 15, g = l >> 4;
  const float CEXP = 0.18033688011112042f;    // (1/8) * log2(e)

  // Q fragments for both query sets (resident for the whole block)
  const long qrow = (long)b * 4096 + qt * 64 + w * 16 + c;
  bh8 qf[2][2];
#pragma unroll
  for (int kk = 0; kk < 2; ++kk) {
    const int col = h * 64 + kk * 32 + g * 8;
    qf[0][kk] = *(const bh8*)(Qb + qrow * 512 + col);
    const float* ap = adapt + qrow * 512 + col;
    f4 x0 = *(const f4*)ap, x1 = *(const f4*)(ap + 4);
    bh8 t;
#pragma unroll
    for (int e = 0; e < 4; ++e) {
      t[e] = (short)rne_bf16(x0[e]);
      t[e + 4] = (short)rne_bf16(x1[e]);
    }
    qf[1][kk] = t;
  }

  float m[2][4], lsum[2][4];
  f4 accv[2][4];
#pragma unroll
  for (int qs = 0; qs < 2; ++qs) {
#pragma unroll
    for (int r = 0; r < 4; ++r) { m[qs][r] = -1e30f; lsum[qs][r] = 0.f; }
#pragma unroll
    for (int dt = 0; dt < 4; ++dt) accv[qs][dt] = (f4){0.f, 0.f, 0.f, 0.f};
  }

  for (int jt0 = 0; jt0 < 16; ++jt0) {
    const long kvbase = ((long)b * 1024 + jt0 * 64) * 1024;
    if (jt0) __syncthreads();
    // K tile: direct-to-LDS with pre-swizzled source
#pragma unroll
    for (int s = 0; s < 2; ++s) {
      const int idx = w * 2 + s;
      const int row = idx * 8 + (l >> 3);
      const int d0 = (((l & 7) ^ row ^ (row >> 3)) & 7) << 3;
      gl_lds16(KV + kvbase + (long)row * 1024 + h * 64 + d0, (char*)Ks + idx * 1024);
    }
    // V tile: coalesced reg load, transposed+swizzled LDS write
#pragma unroll
    for (int p = 0; p < 2; ++p) {
      const int j = p * 32 + (tid >> 3);
      const int d0 = (tid & 7) << 3;
      bh8 v8 = *(const bh8*)(KV + kvbase + (long)j * 1024 + 512 + h * 64 + d0);
#pragma unroll
      for (int e = 0; e < 8; ++e)
        *(short*)((char*)Vt + swz(d0 + e, j)) = v8[e];
    }
    asm volatile("s_waitcnt vmcnt(0)" ::: "memory");
    __syncthreads();

    bh8 kf[4][2], vf[4][2];
#pragma unroll
    for (int t4 = 0; t4 < 4; ++t4)
#pragma unroll
      for (int kk = 0; kk < 2; ++kk) {
        kf[t4][kk] = *(const bh8*)((const char*)Ks + swz(t4 * 16 + c, kk * 32 + g * 8));
        vf[t4][kk] = *(const bh8*)((const char*)Vt + swz(t4 * 16 + c, kk * 32 + g * 8));
      }

    unsigned short* Pw = &Ps[w][0];
#pragma unroll
    for (int qs = 0; qs < 2; ++qs) {
      f4 s4[4];
#pragma unroll
      for (int jt = 0; jt < 4; ++jt) {
        s4[jt] = (f4){0.f, 0.f, 0.f, 0.f};
#pragma unroll
        for (int kk = 0; kk < 2; ++kk)
          s4[jt] = __builtin_amdgcn_mfma_f32_16x16x32_bf16(qf[qs][kk], kf[jt][kk], s4[jt], 0, 0, 0);
      }
      // online softmax; rows live at (g*4 + r), cols at (jt*16 + c)
      float mx[4], fac[4], ps[4];
#pragma unroll
      for (int r = 0; r < 4; ++r) {
        mx[r] = fmaxf(fmaxf(s4[0][r], s4[1][r]), fmaxf(s4[2][r], s4[3][r]));
#pragma unroll
        for (int d = 1; d < 16; d <<= 1) mx[r] = fmaxf(mx[r], __shfl_xor(mx[r], d));
        const float mn = fmaxf(m[qs][r], mx[r]);
        fac[r] = exp2f((m[qs][r] - mn) * CEXP);
        m[qs][r] = mn;
        ps[r] = 0.f;
      }
#pragma unroll
      for (int jt = 0; jt < 4; ++jt)
#pragma unroll
        for (int r = 0; r < 4; ++r) {
          const float p = exp2f((s4[jt][r] - m[qs][r]) * CEXP);
          s4[jt][r] = p;
          ps[r] += p;
        }
#pragma unroll
      for (int r = 0; r < 4; ++r) {
#pragma unroll
        for (int d = 1; d < 16; d <<= 1) ps[r] += __shfl_xor(ps[r], d);
        lsum[qs][r] = lsum[qs][r] * fac[r] + ps[r];
      }
#pragma unroll
      for (int dt = 0; dt < 4; ++dt)
#pragma unroll
        for (int r = 0; r < 4; ++r) accv[qs][dt][r] *= fac[r];
      // P -> LDS (bf16) in A-frag layout, then PV
#pragma unroll
      for (int jt = 0; jt < 4; ++jt)
#pragma unroll
        for (int r = 0; r < 4; ++r)
          Pw[(g * 4 + r) * 72 + jt * 16 + c] = rne_bf16(s4[jt][r]);
      bh8 pf[2];
#pragma unroll
      for (int kk = 0; kk < 2; ++kk)
        pf[kk] = *(const bh8*)(Pw + c * 72 + kk * 32 + g * 8);
#pragma unroll
      for (int dt = 0; dt < 4; ++dt)
#pragma unroll
        for (int kk = 0; kk < 2; ++kk)
          accv[qs][dt] = __builtin_amdgcn_mfma_f32_16x16x32_bf16(pf[kk], vf[dt][kk], accv[qs][dt], 0, 0, 0);
    }
  }

#pragma unroll
  for (int dt = 0; dt < 4; ++dt)
#pragma unroll
    for (int r = 0; r < 4; ++r) {
      const float o = accv[0][dt][r] / lsum[0][r] + accv[1][dt][r] / lsum[1][r];
      const long orow = (long)b * 4096 + qt * 64 + w * 16 + g * 4 + r;
      Ob[orow * 512 + h * 64 + dt * 16 + c] = rne_bf16(o);
    }
}

// ---------- launch ----------
extern "C" void kernel_launch(void* const* d_in, const int* in_sizes, int n_in,
                              void* d_out, int out_size, void* d_ws, size_t ws_size,
                              hipStream_t stream) {
  (void)in_sizes; (void)n_in; (void)out_size; (void)ws_size;
  const float* x       = (const float*)d_in[0];
  const float* context = (const float*)d_in[1];
  const float* adapt   = (const float*)d_in[2];
  const float* Wq      = (const float*)d_in[3];
  const float* Wk      = (const float*)d_in[4];
  const float* Wv      = (const float*)d_in[5];
  const float* Wo      = (const float*)d_in[6];
  const float* bo      = (const float*)d_in[7];
  float* out0 = (float*)d_out;                    // [2,4096,512]
  float* out1 = out0 + (long)2 * 4096 * 512;      // [2,4096,1024]

  char* wp = (char*)d_ws;
  auto take = [&](long elems) { unsigned short* p = (unsigned short*)wp; wp += elems * 2; return p; };
  unsigned short* xb   = take(8192L * 512);   // x bf16
  unsigned short* cb   = take(2048L * 768);   // context bf16
  unsigned short* WqT  = take(512L * 512);    // Wq^T
  unsigned short* WkvT = take(1024L * 768);   // [Wk^T ; Wv^T]
  unsigned short* WoT  = take(512L * 512);    // Wo^T
  unsigned short* Qb   = take(8192L * 512);   // Q projection
  unsigned short* KVb  = take(2048L * 1024);  // K|V projections
  unsigned short* Ob   = take(8192L * 512);   // attention output (merged heads)

  cvt_bf16_kernel<<<1024, 256, 0, stream>>>(x, xb, (8192 * 512) / 4);
  cvt_bf16_kernel<<<512, 256, 0, stream>>>(context, cb, (2048 * 768) / 4);
  transpose_cvt<<<dim3(16, 16), 256, 0, stream>>>(Wq, WqT, 512, 512);
  transpose_cvt<<<dim3(16, 24), 256, 0, stream>>>(Wk, WkvT, 768, 512);
  transpose_cvt<<<dim3(16, 24), 256, 0, stream>>>(Wv, WkvT + 512L * 768, 768, 512);
  transpose_cvt<<<dim3(16, 16), 256, 0, stream>>>(Wo, WoT, 512, 512);

  // Q = x @ Wq                 [8192,512] = [8192,512] x [512,512]
  gemm_bt<0><<<dim3(4, 64, 1), 256, 0, stream>>>(xb, WqT, Qb, 512, 512, 512, 512,
                                                 0, 0, 0, 1.f, nullptr);
  // K|V = context @ [Wk|Wv]    [2048,1024] = [2048,768] x [768,1024]
  gemm_bt<0><<<dim3(8, 16, 1), 256, 0, stream>>>(cb, WkvT, KVb, 768, 768, 768, 1024,
                                                 0, 0, 0, 1.f, nullptr);
  // attn_probs_avg = (SCALE/H) * Q @ K^T over full 512 dims, per batch
  gemm_bt<1><<<dim3(8, 32, 2), 256, 0, stream>>>(Qb, KVb, out1, 512, 512, 1024, 1024,
                                                 4096L * 512, 1024L * 1024, 4096L * 1024,
                                                 0.015625f, nullptr);
  // fused dual-query flash attention
  attn_kernel<<<dim3(64, 8, 2), 256, 0, stream>>>(Qb, adapt, KVb, Ob);
  // out = O @ Wo + bo
  gemm_bt<2><<<dim3(4, 64, 1), 256, 0, stream>>>(Ob, WoT, out0, 512, 512, 512, 512,
                                                 0, 0, 0, 1.f, bo);
}

// Round 2
// 163.088 us; speedup vs baseline: 1.2943x; 1.2943x over previous
//
#include <hip/hip_runtime.h>

// ---------- types ----------
typedef __attribute__((ext_vector_type(8))) short bh8;           // 8 bf16 in 4 VGPRs (MFMA operand)
typedef __attribute__((ext_vector_type(4))) float f4;            // MFMA accumulator
typedef __attribute__((ext_vector_type(4))) unsigned short us4;

__device__ __forceinline__ unsigned short rne_bf16(float x) {
  unsigned int u = __builtin_bit_cast(unsigned int, x);
  u += 0x7fffu + ((u >> 16) & 1u);
  return (unsigned short)(u >> 16);
}

__device__ __forceinline__ unsigned int cvt_pk_bf16(float lo, float hi) {
  unsigned int r;
  asm("v_cvt_pk_bf16_f32 %0, %1, %2" : "=v"(r) : "v"(lo), "v"(hi));
  return r;
}

// Byte offset of element (row, k) in a swizzled [rows][64] bf16 LDS tile (128B rows).
__device__ __forceinline__ int swz(int row, int k) {
  return row * 128 + ((((k >> 3) ^ row ^ (row >> 3)) & 7) << 4) + ((k & 7) << 1);
}

__device__ __forceinline__ void gl_lds16(const void* g, void* l) {
  __builtin_amdgcn_global_load_lds(
      (const __attribute__((address_space(1))) void*)g,
      (__attribute__((address_space(3))) void*)l, 16, 0, 0);
}

// ---------- prepass: fp32 -> bf16 ----------
__global__ void cvt_bf16_kernel(const float* __restrict__ in, unsigned short* __restrict__ out, int n4) {
  int i = blockIdx.x * blockDim.x + threadIdx.x;
  int stride = gridDim.x * blockDim.x;
  for (; i < n4; i += stride) {
    f4 v = *(const f4*)(in + (long)i * 4);
    us4 o;
#pragma unroll
    for (int j = 0; j < 4; ++j) o[j] = rne_bf16(v[j]);
    *(us4*)(out + (long)i * 4) = o;
  }
}

// ---------- prepass: W[K][N] fp32 -> Wt[N][K] bf16 ----------
__global__ void transpose_cvt(const float* __restrict__ in, unsigned short* __restrict__ out,
                              int K, int N) {
  __shared__ float t[32][33];
  int n0 = blockIdx.x * 32, k0 = blockIdx.y * 32;
  int tx = threadIdx.x & 31, ty = threadIdx.x >> 5;  // ty 0..7
#pragma unroll
  for (int r = 0; r < 32; r += 8)
    t[ty + r][tx] = in[(long)(k0 + ty + r) * N + n0 + tx];
  __syncthreads();
#pragma unroll
  for (int r = 0; r < 32; r += 8)
    out[(long)(n0 + ty + r) * K + k0 + tx] = rne_bf16(t[tx][ty + r]);
}

// ---------- generic bf16 GEMM: C[m][n] = sum_k A[m][k] * Bt[n][k] ----------
// MODE 0: store bf16.  MODE 1: store f32 * scale.  MODE 2: store f32 + bias[n].
template <int MODE>
__global__ __launch_bounds__(256, 2) void gemm_bt(
    const unsigned short* __restrict__ A, const unsigned short* __restrict__ Bt,
    void* __restrict__ Cv, int K, int lda, int ldb, int ldc,
    long astr, long bstr, long cstr, float scale, const float* __restrict__ bias) {
  __shared__ unsigned short As[128 * 64];
  __shared__ unsigned short Bs[128 * 64];
  const int tid = threadIdx.x, w = tid >> 6, l = tid & 63;
  const int c = l & 15, g = l >> 4;
  const int m0 = blockIdx.y * 128, n0 = blockIdx.x * 128;
  const unsigned short* Ab = A + (long)blockIdx.z * astr;
  const unsigned short* Bb = Bt + (long)blockIdx.z * bstr;

  f4 acc[4][4];
#pragma unroll
  for (int i = 0; i < 4; ++i)
#pragma unroll
    for (int j = 0; j < 4; ++j) acc[i][j] = (f4){0.f, 0.f, 0.f, 0.f};

  const int nkt = K >> 6;
  for (int kt = 0; kt < nkt; ++kt) {
    if (kt) __syncthreads();
#pragma unroll
    for (int s = 0; s < 4; ++s) {
      const int idx = w * 4 + s;               // wave-uniform LDS dest
      const int row = idx * 8 + (l >> 3);
      const int k0 = (((l & 7) ^ row ^ (row >> 3)) & 7) << 3;  // inverse swizzle on source
      gl_lds16(Ab + (long)(m0 + row) * lda + kt * 64 + k0, (char*)As + idx * 1024);
      gl_lds16(Bb + (long)(n0 + row) * ldb + kt * 64 + k0, (char*)Bs + idx * 1024);
    }
    asm volatile("s_waitcnt vmcnt(0)" ::: "memory");
    __syncthreads();
#pragma unroll
    for (int kk = 0; kk < 2; ++kk) {
      const int k = kk * 32 + g * 8;
      bh8 af[4], bfr[4];
#pragma unroll
      for (int i = 0; i < 4; ++i) {
        af[i] = *(const bh8*)((const char*)As + swz((w >> 1) * 64 + i * 16 + c, k));
        bfr[i] = *(const bh8*)((const char*)Bs + swz((w & 1) * 64 + i * 16 + c, k));
      }
#pragma unroll
      for (int i = 0; i < 4; ++i)
#pragma unroll
        for (int j = 0; j < 4; ++j)
          acc[i][j] = __builtin_amdgcn_mfma_f32_16x16x32_bf16(af[i], bfr[j], acc[i][j], 0, 0, 0);
    }
  }

  const int rbase = m0 + (w >> 1) * 64, cbase = n0 + (w & 1) * 64;
#pragma unroll
  for (int i = 0; i < 4; ++i)
#pragma unroll
    for (int j = 0; j < 4; ++j)
#pragma unroll
      for (int r = 0; r < 4; ++r) {
        const long row = rbase + i * 16 + g * 4 + r;
        const long col = cbase + j * 16 + c;
        const float v = acc[i][j][r];
        if (MODE == 0) {
          ((unsigned short*)Cv + (long)blockIdx.z * cstr)[row * ldc + col] = rne_bf16(v);
        } else if (MODE == 1) {
          ((float*)Cv + (long)blockIdx.z * cstr)[row * ldc + col] = v * scale;
        } else {
          ((float*)Cv)[row * ldc + col] = v + bias[col];
        }
      }
}

// ---------- fused two-query flash attention (swapped-QK^T, per-lane softmax) ----------
// Qb: [8192][512] bf16 (projected).  adapt: [8192][512] fp32 (raw second query).
// KV: [2048][1024] bf16 (cols 0..511 = K-proj, 512..1023 = V-proj).
// Ob: [8192][512] bf16, merged-head attention output (sum of both passes, each normalized).
__global__ __launch_bounds__(256, 2) void attn_kernel(
    const unsigned short* __restrict__ Qb, const float* __restrict__ adapt,
    const unsigned short* __restrict__ KV, unsigned short* __restrict__ Ob) {
  __shared__ unsigned short Ks[64 * 64];      // swizzled [j][d]
  __shared__ unsigned short Vt[64 * 64];      // swizzled, transposed: (row=d, col=j)
  __shared__ unsigned short Ps[4][16 * 72];   // per-wave P[q=16][kv=64], stride 72 shorts
  const int qt = blockIdx.x, h = blockIdx.y, b = blockIdx.z;
  const int tid = threadIdx.x, w = tid >> 6, l = tid & 63;
  const int c = l & 15, g = l >> 4;
  const float CEXP = 0.18033688011112042f;    // (1/8) * log2(e)
  const float THR = 44.3614195558365f;        // 8 / CEXP in raw-logit units

  // Q fragments for both query sets (lane c = q row within the wave's 16-row tile)
  const long qrow = (long)b * 4096 + qt * 64 + w * 16 + c;
  bh8 qf[2][2];
#pragma unroll
  for (int kk = 0; kk < 2; ++kk) {
    const int col = h * 64 + kk * 32 + g * 8;
    qf[0][kk] = *(const bh8*)(Qb + qrow * 512 + col);
    const float* ap = adapt + qrow * 512 + col;
    f4 x0 = *(const f4*)ap, x1 = *(const f4*)(ap + 4);
    bh8 t;
#pragma unroll
    for (int e = 0; e < 4; ++e) {
      t[e] = (short)rne_bf16(x0[e]);
      t[e + 4] = (short)rne_bf16(x1[e]);
    }
    qf[1][kk] = t;
  }

  float m[2], lsum[2];
  f4 accv[2][4];                               // O^T: reg dim = d (dt*16+g*4+r), lane c = q
#pragma unroll
  for (int qs = 0; qs < 2; ++qs) {
    m[qs] = -1e30f; lsum[qs] = 0.f;
#pragma unroll
    for (int dt = 0; dt < 4; ++dt) accv[qs][dt] = (f4){0.f, 0.f, 0.f, 0.f};
  }

  for (int jt0 = 0; jt0 < 16; ++jt0) {
    const long kvbase = ((long)b * 1024 + jt0 * 64) * 1024;
    if (jt0) __syncthreads();
    // K tile: direct-to-LDS with pre-swizzled source
#pragma unroll
    for (int s = 0; s < 2; ++s) {
      const int idx = w * 2 + s;
      const int row = idx * 8 + (l >> 3);
      const int d0 = (((l & 7) ^ row ^ (row >> 3)) & 7) << 3;
      gl_lds16(KV + kvbase + (long)row * 1024 + h * 64 + d0, (char*)Ks + idx * 1024);
    }
    // V tile: coalesced reg load, transposed+swizzled LDS write
#pragma unroll
    for (int p = 0; p < 2; ++p) {
      const int j = p * 32 + (tid >> 3);
      const int d0 = (tid & 7) << 3;
      bh8 v8 = *(const bh8*)(KV + kvbase + (long)j * 1024 + 512 + h * 64 + d0);
#pragma unroll
      for (int e = 0; e < 8; ++e)
        *(short*)((char*)Vt + swz(d0 + e, j)) = v8[e];
    }
    asm volatile("s_waitcnt vmcnt(0)" ::: "memory");
    __syncthreads();

    bh8 kf[4][2], vf[4][2];
#pragma unroll
    for (int t4 = 0; t4 < 4; ++t4)
#pragma unroll
      for (int kk = 0; kk < 2; ++kk) {
        kf[t4][kk] = *(const bh8*)((const char*)Ks + swz(t4 * 16 + c, kk * 32 + g * 8));
        vf[t4][kk] = *(const bh8*)((const char*)Vt + swz(t4 * 16 + c, kk * 32 + g * 8));
      }

    unsigned short* Pw = &Ps[w][0];
#pragma unroll
    for (int qs = 0; qs < 2; ++qs) {
      // S^T tiles: reg dim = kv (jt*16 + g*4 + r), lane c = q
      f4 s4[4];
#pragma unroll
      for (int jt = 0; jt < 4; ++jt) {
        s4[jt] = (f4){0.f, 0.f, 0.f, 0.f};
#pragma unroll
        for (int kk = 0; kk < 2; ++kk)
          s4[jt] = __builtin_amdgcn_mfma_f32_16x16x32_bf16(kf[jt][kk], qf[qs][kk], s4[jt], 0, 0, 0);
      }
      // per-lane max over this lane's 16 kv scores, then combine across g (2 shuffles)
      float mx = s4[0][0];
#pragma unroll
      for (int jt = 0; jt < 4; ++jt)
#pragma unroll
        for (int r = 0; r < 4; ++r) mx = fmaxf(mx, s4[jt][r]);
      mx = fmaxf(mx, __shfl_xor(mx, 16));
      mx = fmaxf(mx, __shfl_xor(mx, 32));
      // defer-max: rescale only when the running max actually grows materially
      if (!__all(mx <= m[qs] + THR)) {
        const float mn = fmaxf(m[qs], mx);
        const float fac = exp2f((m[qs] - mn) * CEXP);
        lsum[qs] *= fac;
#pragma unroll
        for (int dt = 0; dt < 4; ++dt)
#pragma unroll
          for (int r = 0; r < 4; ++r) accv[qs][dt][r] *= fac;
        m[qs] = mn;
      }
      const float mb = m[qs] * CEXP;
      float ps = 0.f;
#pragma unroll
      for (int jt = 0; jt < 4; ++jt)
#pragma unroll
        for (int r = 0; r < 4; ++r) {
          const float p = exp2f(s4[jt][r] * CEXP - mb);
          s4[jt][r] = p;
          ps += p;
        }
      ps += __shfl_xor(ps, 16);
      ps += __shfl_xor(ps, 32);
      lsum[qs] += ps;
      // P -> LDS as P[q=c][kv], packed bf16 pairs, 4x ds_write_b64
#pragma unroll
      for (int jt = 0; jt < 4; ++jt) {
        uint2 pk;
        pk.x = cvt_pk_bf16(s4[jt][0], s4[jt][1]);
        pk.y = cvt_pk_bf16(s4[jt][2], s4[jt][3]);
        *(uint2*)(Pw + c * 72 + jt * 16 + g * 4) = pk;
      }
      bh8 pf[2];
#pragma unroll
      for (int kk = 0; kk < 2; ++kk)
        pf[kk] = *(const bh8*)(Pw + c * 72 + kk * 32 + g * 8);
      // O^T += V^T . P^T : mfma(vf, pf) -> reg dim = d, lane = q
#pragma unroll
      for (int dt = 0; dt < 4; ++dt)
#pragma unroll
        for (int kk = 0; kk < 2; ++kk)
          accv[qs][dt] = __builtin_amdgcn_mfma_f32_16x16x32_bf16(vf[dt][kk], pf[kk], accv[qs][dt], 0, 0, 0);
    }
  }

  const float i0 = 1.0f / lsum[0], i1 = 1.0f / lsum[1];
  const long orow = (long)b * 4096 + qt * 64 + w * 16 + c;
#pragma unroll
  for (int dt = 0; dt < 4; ++dt) {
    float v0 = accv[0][dt][0] * i0 + accv[1][dt][0] * i1;
    float v1 = accv[0][dt][1] * i0 + accv[1][dt][1] * i1;
    float v2 = accv[0][dt][2] * i0 + accv[1][dt][2] * i1;
    float v3 = accv[0][dt][3] * i0 + accv[1][dt][3] * i1;
    uint2 o;
    o.x = cvt_pk_bf16(v0, v1);
    o.y = cvt_pk_bf16(v2, v3);
    *(uint2*)(Ob + orow * 512 + h * 64 + dt * 16 + g * 4) = o;
  }
}

// ---------- launch ----------
extern "C" void kernel_launch(void* const* d_in, const int* in_sizes, int n_in,
                              void* d_out, int out_size, void* d_ws, size_t ws_size,
                              hipStream_t stream) {
  (void)in_sizes; (void)n_in; (void)out_size; (void)ws_size;
  const float* x       = (const float*)d_in[0];
  const float* context = (const float*)d_in[1];
  const float* adapt   = (const float*)d_in[2];
  const float* Wq      = (const float*)d_in[3];
  const float* Wk      = (const float*)d_in[4];
  const float* Wv      = (const float*)d_in[5];
  const float* Wo      = (const float*)d_in[6];
  const float* bo      = (const float*)d_in[7];
  float* out0 = (float*)d_out;                    // [2,4096,512]
  float* out1 = out0 + (long)2 * 4096 * 512;      // [2,4096,1024]

  char* wp = (char*)d_ws;
  auto take = [&](long elems) { unsigned short* p = (unsigned short*)wp; wp += elems * 2; return p; };
  unsigned short* xb   = take(8192L * 512);   // x bf16
  unsigned short* cb   = take(2048L * 768);   // context bf16
  unsigned short* WqT  = take(512L * 512);    // Wq^T
  unsigned short* WkvT = take(1024L * 768);   // [Wk^T ; Wv^T]
  unsigned short* WoT  = take(512L * 512);    // Wo^T
  unsigned short* Qb   = take(8192L * 512);   // Q projection
  unsigned short* KVb  = take(2048L * 1024);  // K|V projections
  unsigned short* Ob   = take(8192L * 512);   // attention output (merged heads)

  cvt_bf16_kernel<<<1024, 256, 0, stream>>>(x, xb, (8192 * 512) / 4);
  cvt_bf16_kernel<<<512, 256, 0, stream>>>(context, cb, (2048 * 768) / 4);
  transpose_cvt<<<dim3(16, 16), 256, 0, stream>>>(Wq, WqT, 512, 512);
  transpose_cvt<<<dim3(16, 24), 256, 0, stream>>>(Wk, WkvT, 768, 512);
  transpose_cvt<<<dim3(16, 24), 256, 0, stream>>>(Wv, WkvT + 512L * 768, 768, 512);
  transpose_cvt<<<dim3(16, 16), 256, 0, stream>>>(Wo, WoT, 512, 512);

  // Q = x @ Wq                 [8192,512] = [8192,512] x [512,512]
  gemm_bt<0><<<dim3(4, 64, 1), 256, 0, stream>>>(xb, WqT, Qb, 512, 512, 512, 512,
                                                 0, 0, 0, 1.f, nullptr);
  // K|V = context @ [Wk|Wv]    [2048,1024] = [2048,768] x [768,1024]
  gemm_bt<0><<<dim3(8, 16, 1), 256, 0, stream>>>(cb, WkvT, KVb, 768, 768, 768, 1024,
                                                 0, 0, 0, 1.f, nullptr);
  // attn_probs_avg = (SCALE/H) * Q @ K^T over full 512 dims, per batch
  gemm_bt<1><<<dim3(8, 32, 2), 256, 0, stream>>>(Qb, KVb, out1, 512, 512, 1024, 1024,
                                                 4096L * 512, 1024L * 1024, 4096L * 1024,
                                                 0.015625f, nullptr);
  // fused dual-query flash attention
  attn_kernel<<<dim3(64, 8, 2), 256, 0, stream>>>(Qb, adapt, KVb, Ob);
  // out = O @ Wo + bo
  gemm_bt<2><<<dim3(4, 64, 1), 256, 0, stream>>>(Ob, WoT, out0, 512, 512, 512, 512,
                                                 0, 0, 0, 1.f, bo);
}

// Round 3
// 159.060 us; speedup vs baseline: 1.3270x; 1.0253x over previous
//
#include <hip/hip_runtime.h>

// ---------- types ----------
typedef __attribute__((ext_vector_type(8))) short bh8;           // 8 bf16 in 4 VGPRs (MFMA operand)
typedef __attribute__((ext_vector_type(4))) float f4;            // MFMA accumulator
typedef __attribute__((ext_vector_type(4))) unsigned short us4;

__device__ __forceinline__ unsigned short rne_bf16(float x) {
  unsigned int u = __builtin_bit_cast(unsigned int, x);
  u += 0x7fffu + ((u >> 16) & 1u);
  return (unsigned short)(u >> 16);
}

__device__ __forceinline__ unsigned int cvt_pk_bf16(float lo, float hi) {
  unsigned int r;
  asm("v_cvt_pk_bf16_f32 %0, %1, %2" : "=v"(r) : "v"(lo), "v"(hi));
  return r;
}

// Byte offset of element (row, k) in a swizzled [rows][64] bf16 LDS tile (128B rows).
__device__ __forceinline__ int swz(int row, int k) {
  return row * 128 + ((((k >> 3) ^ row ^ (row >> 3)) & 7) << 4) + ((k & 7) << 1);
}

__device__ __forceinline__ void gl_lds16(const void* g, void* l) {
  __builtin_amdgcn_global_load_lds(
      (const __attribute__((address_space(1))) void*)g,
      (__attribute__((address_space(3))) void*)l, 16, 0, 0);
}

// ---------- prepass: fp32 -> bf16 ----------
__global__ void cvt_bf16_kernel(const float* __restrict__ in, unsigned short* __restrict__ out, int n4) {
  int i = blockIdx.x * blockDim.x + threadIdx.x;
  int stride = gridDim.x * blockDim.x;
  for (; i < n4; i += stride) {
    f4 v = *(const f4*)(in + (long)i * 4);
    us4 o;
#pragma unroll
    for (int j = 0; j < 4; ++j) o[j] = rne_bf16(v[j]);
    *(us4*)(out + (long)i * 4) = o;
  }
}

// ---------- prepass: W[K][N] fp32 -> Wt[N][K] bf16 ----------
__global__ void transpose_cvt(const float* __restrict__ in, unsigned short* __restrict__ out,
                              int K, int N) {
  __shared__ float t[32][33];
  int n0 = blockIdx.x * 32, k0 = blockIdx.y * 32;
  int tx = threadIdx.x & 31, ty = threadIdx.x >> 5;  // ty 0..7
#pragma unroll
  for (int r = 0; r < 32; r += 8)
    t[ty + r][tx] = in[(long)(k0 + ty + r) * N + n0 + tx];
  __syncthreads();
#pragma unroll
  for (int r = 0; r < 32; r += 8)
    out[(long)(n0 + ty + r) * K + k0 + tx] = rne_bf16(t[tx][ty + r]);
}

// ---------- prepass: V^T from KVb.  VTb[d][b*1024+j] = KVb[(b*1024+j)][512+d] ----------
__global__ void transpose_v(const unsigned short* __restrict__ KVb, unsigned short* __restrict__ VTb) {
  __shared__ unsigned short t[32][34];
  int j0 = blockIdx.x * 32, d0 = blockIdx.y * 32;
  int tx = threadIdx.x & 31, ty = threadIdx.x >> 5;  // 0..7
#pragma unroll
  for (int r = 0; r < 32; r += 8)
    t[ty + r][tx] = KVb[(long)(j0 + ty + r) * 1024 + 512 + d0 + tx];
  __syncthreads();
#pragma unroll
  for (int r = 0; r < 32; r += 8)
    VTb[(long)(d0 + ty + r) * 2048 + j0 + tx] = t[tx][ty + r];
}

// ---------- generic bf16 GEMM: C[m][n] = sum_k A[m][k] * Bt[n][k] ----------
// MODE 0: store bf16.  MODE 1: store f32 * scale.  MODE 2: store f32 + bias[n].
template <int MODE>
__global__ __launch_bounds__(256, 2) void gemm_bt(
    const unsigned short* __restrict__ A, const unsigned short* __restrict__ Bt,
    void* __restrict__ Cv, int K, int lda, int ldb, int ldc,
    long astr, long bstr, long cstr, float scale, const float* __restrict__ bias) {
  __shared__ unsigned short As[128 * 64];
  __shared__ unsigned short Bs[128 * 64];
  const int tid = threadIdx.x, w = tid >> 6, l = tid & 63;
  const int c = l & 15, g = l >> 4;
  const int m0 = blockIdx.y * 128, n0 = blockIdx.x * 128;
  const unsigned short* Ab = A + (long)blockIdx.z * astr;
  const unsigned short* Bb = Bt + (long)blockIdx.z * bstr;

  f4 acc[4][4];
#pragma unroll
  for (int i = 0; i < 4; ++i)
#pragma unroll
    for (int j = 0; j < 4; ++j) acc[i][j] = (f4){0.f, 0.f, 0.f, 0.f};

  const int nkt = K >> 6;
  for (int kt = 0; kt < nkt; ++kt) {
    if (kt) __syncthreads();
#pragma unroll
    for (int s = 0; s < 4; ++s) {
      const int idx = w * 4 + s;               // wave-uniform LDS dest
      const int row = idx * 8 + (l >> 3);
      const int k0 = (((l & 7) ^ row ^ (row >> 3)) & 7) << 3;  // inverse swizzle on source
      gl_lds16(Ab + (long)(m0 + row) * lda + kt * 64 + k0, (char*)As + idx * 1024);
      gl_lds16(Bb + (long)(n0 + row) * ldb + kt * 64 + k0, (char*)Bs + idx * 1024);
    }
    asm volatile("s_waitcnt vmcnt(0)" ::: "memory");
    __syncthreads();
#pragma unroll
    for (int kk = 0; kk < 2; ++kk) {
      const int k = kk * 32 + g * 8;
      bh8 af[4], bfr[4];
#pragma unroll
      for (int i = 0; i < 4; ++i) {
        af[i] = *(const bh8*)((const char*)As + swz((w >> 1) * 64 + i * 16 + c, k));
        bfr[i] = *(const bh8*)((const char*)Bs + swz((w & 1) * 64 + i * 16 + c, k));
      }
#pragma unroll
      for (int i = 0; i < 4; ++i)
#pragma unroll
        for (int j = 0; j < 4; ++j)
          acc[i][j] = __builtin_amdgcn_mfma_f32_16x16x32_bf16(af[i], bfr[j], acc[i][j], 0, 0, 0);
    }
  }

  const int rbase = m0 + (w >> 1) * 64, cbase = n0 + (w & 1) * 64;
#pragma unroll
  for (int i = 0; i < 4; ++i)
#pragma unroll
    for (int j = 0; j < 4; ++j)
#pragma unroll
      for (int r = 0; r < 4; ++r) {
        const long row = rbase + i * 16 + g * 4 + r;
        const long col = cbase + j * 16 + c;
        const float v = acc[i][j][r];
        if (MODE == 0) {
          ((unsigned short*)Cv + (long)blockIdx.z * cstr)[row * ldc + col] = rne_bf16(v);
        } else if (MODE == 1) {
          ((float*)Cv + (long)blockIdx.z * cstr)[row * ldc + col] = v * scale;
        } else {
          ((float*)Cv)[row * ldc + col] = v + bias[col];
        }
      }
}

// ---------- fused two-query flash attention (swapped-QK^T, dbuf staging, V^T direct) ----------
// Qb: [8192][512] bf16.  adapt: [8192][512] fp32.  KV: [2048][1024] bf16 (K in cols 0..511).
// VT: [512][2048] bf16 (V^T, col = b*1024 + j).  Ob: [8192][512] bf16.
__global__ __launch_bounds__(256, 3) void attn_kernel(
    const unsigned short* __restrict__ Qb, const float* __restrict__ adapt,
    const unsigned short* __restrict__ KV, const unsigned short* __restrict__ VT,
    unsigned short* __restrict__ Ob) {
  __shared__ unsigned short Ks[2][64 * 64];   // swizzled [j][d]
  __shared__ unsigned short Vs[2][64 * 64];   // swizzled [d][j]  (from V^T)
  __shared__ unsigned short Ps[4][16 * 64];   // per-wave P[q=16][kv=64], swizzled rows
  const int qt = blockIdx.x, h = blockIdx.y, b = blockIdx.z;
  const int tid = threadIdx.x, w = tid >> 6, l = tid & 63;
  const int c = l & 15, g = l >> 4;
  const float CEXP = 0.18033688011112042f;    // (1/8) * log2(e)
  const float THR = 44.3614195558365f;        // 8 / CEXP in raw-logit units

  const unsigned short* Kg = KV + ((long)b * 1024) * 1024 + h * 64;  // + j*1024
  const unsigned short* Vg = VT + (long)h * 64 * 2048 + b * 1024;    // + d*2048 + j

  auto stage = [&](int buf, int jt0) {
#pragma unroll
    for (int s = 0; s < 2; ++s) {
      const int idx = w * 2 + s;
      const int row = idx * 8 + (l >> 3);
      const int c0 = (((l & 7) ^ row ^ (row >> 3)) & 7) << 3;  // inverse swizzle on source
      gl_lds16(Kg + ((long)jt0 * 64 + row) * 1024 + c0, (char*)&Ks[buf][0] + idx * 1024);
      gl_lds16(Vg + (long)row * 2048 + jt0 * 64 + c0, (char*)&Vs[buf][0] + idx * 1024);
    }
  };

  stage(0, 0);

  // Q fragments for both query sets (lane c = q row within the wave's 16-row tile)
  const long qrow = (long)b * 4096 + qt * 64 + w * 16 + c;
  bh8 qf[2][2];
#pragma unroll
  for (int kk = 0; kk < 2; ++kk) {
    const int col = h * 64 + kk * 32 + g * 8;
    qf[0][kk] = *(const bh8*)(Qb + qrow * 512 + col);
    const float* ap = adapt + qrow * 512 + col;
    f4 x0 = *(const f4*)ap, x1 = *(const f4*)(ap + 4);
    bh8 t;
#pragma unroll
    for (int e = 0; e < 4; ++e) {
      t[e] = (short)rne_bf16(x0[e]);
      t[e + 4] = (short)rne_bf16(x1[e]);
    }
    qf[1][kk] = t;
  }

  float m[2], lsum[2];
  f4 accv[2][4];                               // O^T: reg dim = d (dt*16+g*4+r), lane c = q
#pragma unroll
  for (int qs = 0; qs < 2; ++qs) {
    m[qs] = -1e30f; lsum[qs] = 0.f;
#pragma unroll
    for (int dt = 0; dt < 4; ++dt) accv[qs][dt] = (f4){0.f, 0.f, 0.f, 0.f};
  }

  asm volatile("s_waitcnt vmcnt(0)" ::: "memory");
  __syncthreads();

  for (int jt0 = 0; jt0 < 16; ++jt0) {
    const int cur = jt0 & 1;
    if (jt0 < 15) stage(cur ^ 1, jt0 + 1);     // prefetch next tile under compute

    bh8 kf[4][2], vf[4][2];
#pragma unroll
    for (int t4 = 0; t4 < 4; ++t4)
#pragma unroll
      for (int kk = 0; kk < 2; ++kk) {
        kf[t4][kk] = *(const bh8*)((const char*)&Ks[cur][0] + swz(t4 * 16 + c, kk * 32 + g * 8));
        vf[t4][kk] = *(const bh8*)((const char*)&Vs[cur][0] + swz(t4 * 16 + c, kk * 32 + g * 8));
      }

    unsigned short* Pw = &Ps[w][0];
#pragma unroll
    for (int qs = 0; qs < 2; ++qs) {
      // S^T tiles: reg dim = kv (jt*16 + g*4 + r), lane c = q
      f4 s4[4];
      __builtin_amdgcn_s_setprio(1);
#pragma unroll
      for (int jt = 0; jt < 4; ++jt) {
        s4[jt] = (f4){0.f, 0.f, 0.f, 0.f};
#pragma unroll
        for (int kk = 0; kk < 2; ++kk)
          s4[jt] = __builtin_amdgcn_mfma_f32_16x16x32_bf16(kf[jt][kk], qf[qs][kk], s4[jt], 0, 0, 0);
      }
      __builtin_amdgcn_s_setprio(0);
      // per-lane max over 16 kv scores, combine across g (2 shuffles)
      float mx = s4[0][0];
#pragma unroll
      for (int jt = 0; jt < 4; ++jt)
#pragma unroll
        for (int r = 0; r < 4; ++r) mx = fmaxf(mx, s4[jt][r]);
      mx = fmaxf(mx, __shfl_xor(mx, 16));
      mx = fmaxf(mx, __shfl_xor(mx, 32));
      // defer-max: rescale only when the running max grows materially
      if (!__all(mx <= m[qs] + THR)) {
        const float mn = fmaxf(m[qs], mx);
        const float fac = exp2f((m[qs] - mn) * CEXP);
        lsum[qs] *= fac;
#pragma unroll
        for (int dt = 0; dt < 4; ++dt)
#pragma unroll
          for (int r = 0; r < 4; ++r) accv[qs][dt][r] *= fac;
        m[qs] = mn;
      }
      const float mb = m[qs] * CEXP;
      float ps = 0.f;
#pragma unroll
      for (int jt = 0; jt < 4; ++jt)
#pragma unroll
        for (int r = 0; r < 4; ++r) {
          const float p = exp2f(s4[jt][r] * CEXP - mb);
          s4[jt][r] = p;
          ps += p;
        }
      ps += __shfl_xor(ps, 16);
      ps += __shfl_xor(ps, 32);
      lsum[qs] += ps;
      // P -> LDS as P[q=c][kv], swizzled rows, packed bf16, 4x ds_write_b64
#pragma unroll
      for (int jt = 0; jt < 4; ++jt) {
        uint2 pk;
        pk.x = cvt_pk_bf16(s4[jt][0], s4[jt][1]);
        pk.y = cvt_pk_bf16(s4[jt][2], s4[jt][3]);
        *(uint2*)((char*)Pw + swz(c, jt * 16 + g * 4)) = pk;
      }
      bh8 pf[2];
#pragma unroll
      for (int kk = 0; kk < 2; ++kk)
        pf[kk] = *(const bh8*)((const char*)Pw + swz(c, kk * 32 + g * 8));
      // O^T += V^T . P^T : mfma(vf, pf) -> reg dim = d, lane = q
      __builtin_amdgcn_s_setprio(1);
#pragma unroll
      for (int dt = 0; dt < 4; ++dt)
#pragma unroll
        for (int kk = 0; kk < 2; ++kk)
          accv[qs][dt] = __builtin_amdgcn_mfma_f32_16x16x32_bf16(vf[dt][kk], pf[kk], accv[qs][dt], 0, 0, 0);
      __builtin_amdgcn_s_setprio(0);
    }
    if (jt0 < 15) {
      asm volatile("s_waitcnt vmcnt(0)" ::: "memory");
      __syncthreads();
    }
  }

  const float i0 = 1.0f / lsum[0], i1 = 1.0f / lsum[1];
  const long orow = (long)b * 4096 + qt * 64 + w * 16 + c;
#pragma unroll
  for (int dt = 0; dt < 4; ++dt) {
    float v0 = accv[0][dt][0] * i0 + accv[1][dt][0] * i1;
    float v1 = accv[0][dt][1] * i0 + accv[1][dt][1] * i1;
    float v2 = accv[0][dt][2] * i0 + accv[1][dt][2] * i1;
    float v3 = accv[0][dt][3] * i0 + accv[1][dt][3] * i1;
    uint2 o;
    o.x = cvt_pk_bf16(v0, v1);
    o.y = cvt_pk_bf16(v2, v3);
    *(uint2*)(Ob + orow * 512 + h * 64 + dt * 16 + g * 4) = o;
  }
}

// ---------- launch ----------
extern "C" void kernel_launch(void* const* d_in, const int* in_sizes, int n_in,
                              void* d_out, int out_size, void* d_ws, size_t ws_size,
                              hipStream_t stream) {
  (void)in_sizes; (void)n_in; (void)out_size; (void)ws_size;
  const float* x       = (const float*)d_in[0];
  const float* context = (const float*)d_in[1];
  const float* adapt   = (const float*)d_in[2];
  const float* Wq      = (const float*)d_in[3];
  const float* Wk      = (const float*)d_in[4];
  const float* Wv      = (const float*)d_in[5];
  const float* Wo      = (const float*)d_in[6];
  const float* bo      = (const float*)d_in[7];
  float* out0 = (float*)d_out;                    // [2,4096,512]
  float* out1 = out0 + (long)2 * 4096 * 512;      // [2,4096,1024]

  char* wp = (char*)d_ws;
  auto take = [&](long elems) { unsigned short* p = (unsigned short*)wp; wp += elems * 2; return p; };
  unsigned short* xb   = take(8192L * 512);   // x bf16
  unsigned short* cb   = take(2048L * 768);   // context bf16
  unsigned short* WqT  = take(512L * 512);    // Wq^T
  unsigned short* WkvT = take(1024L * 768);   // [Wk^T ; Wv^T]
  unsigned short* WoT  = take(512L * 512);    // Wo^T
  unsigned short* Qb   = take(8192L * 512);   // Q projection
  unsigned short* KVb  = take(2048L * 1024);  // K|V projections
  unsigned short* VTb  = take(512L * 2048);   // V^T
  unsigned short* Ob   = take(8192L * 512);   // attention output (merged heads)

  cvt_bf16_kernel<<<1024, 256, 0, stream>>>(x, xb, (8192 * 512) / 4);
  cvt_bf16_kernel<<<512, 256, 0, stream>>>(context, cb, (2048 * 768) / 4);
  transpose_cvt<<<dim3(16, 16), 256, 0, stream>>>(Wq, WqT, 512, 512);
  transpose_cvt<<<dim3(16, 24), 256, 0, stream>>>(Wk, WkvT, 768, 512);
  transpose_cvt<<<dim3(16, 24), 256, 0, stream>>>(Wv, WkvT + 512L * 768, 768, 512);
  transpose_cvt<<<dim3(16, 16), 256, 0, stream>>>(Wo, WoT, 512, 512);

  // Q = x @ Wq                 [8192,512] = [8192,512] x [512,512]
  gemm_bt<0><<<dim3(4, 64, 1), 256, 0, stream>>>(xb, WqT, Qb, 512, 512, 512, 512,
                                                 0, 0, 0, 1.f, nullptr);
  // K|V = context @ [Wk|Wv]    [2048,1024] = [2048,768] x [768,1024]
  gemm_bt<0><<<dim3(8, 16, 1), 256, 0, stream>>>(cb, WkvT, KVb, 768, 768, 768, 1024,
                                                 0, 0, 0, 1.f, nullptr);
  // V^T for the attention PV pass
  transpose_v<<<dim3(64, 16), 256, 0, stream>>>(KVb, VTb);
  // attn_probs_avg = (SCALE/H) * Q @ K^T over full 512 dims, per batch
  gemm_bt<1><<<dim3(8, 32, 2), 256, 0, stream>>>(Qb, KVb, out1, 512, 512, 1024, 1024,
                                                 4096L * 512, 1024L * 1024, 4096L * 1024,
                                                 0.015625f, nullptr);
  // fused dual-query flash attention
  attn_kernel<<<dim3(64, 8, 2), 256, 0, stream>>>(Qb, adapt, KVb, VTb, Ob);
  // out = O @ Wo + bo
  gemm_bt<2><<<dim3(4, 64, 1), 256, 0, stream>>>(Ob, WoT, out0, 512, 512, 512, 512,
                                                 0, 0, 0, 1.f, bo);
}